// Round 4
// baseline (255.195 us; speedup 1.0000x reference)
//
#include <hip/hip_runtime.h>
#include <hip/hip_bf16.h>

// ---------------------------------------------------------------------------
// RPN_Modulator fused pipeline (3 kernels):
//   k_q   : qpart[s,k,bi,c] = partial_c' modulator[bi,c'] * pm_w[k,c,c']   (4-way K-split)
//   k_w2  : w2[k,bi,o,c] = bf16(po_w[k,o,c] * (sum_s qpart + pm_b[k,c]))   (row-major)
//   k_gemm: out[k,bi,o,n] = sum_c w2[o,c]*bf16(feats[k][b,c,n]) + po_b[k,o]
//
// Round-3: PERSISTENT double-buffered k_gemm. 512 blocks (2/CU) loop over
// 2136 jobs = (64n-tile, b). LDS 2 x [64n][256c] bf16 (h-swizzled, 32KB each).
// Per job: inst0 -> issue next tile's 8 f32x4 loads (reg-staged, pinned after
// inst0 so in-order vmcnt keeps them independent of store drain) -> inst1 ->
// ds_write next buffer -> inst2,3 -> raw s_barrier + lgkmcnt(0) ONLY (stores
// never drained at barriers; they float across jobs). Removes the exposed
// stage phase, the __syncthreads vmcnt(0) store drain, and shrinks the
// scheduling tail (uniform ~13us jobs, 4-5 per worker). Same 32x32x16 MFMA,
// same swizzle, same full-line NT stores as the verified round-2 kernel.
// ---------------------------------------------------------------------------

typedef __bf16 bf16x8 __attribute__((ext_vector_type(8)));
typedef float  f32x4  __attribute__((ext_vector_type(4)));
typedef float  f32x16 __attribute__((ext_vector_type(16)));
typedef unsigned short u16;

#define NWORK 512
#define NJOBS 2136   // 534 tiles * 4 b

__device__ __forceinline__ unsigned pack2(float lo, float hi) {
    __hip_bfloat162 h = __float22bfloat162_rn(make_float2(lo, hi));
    union { __hip_bfloat162 h; unsigned u; } cv; cv.h = h; return cv.u;
}

// tiles-of-64 per level: {400,100,25,7,2}, total 534
__device__ __forceinline__ void decode_tile(int x, int& k, int& nt, int& N, size_t& oo) {
    if (x < 400)      { k = 0; nt = x;       N = 25600; oo = 0; }
    else if (x < 500) { k = 1; nt = x - 400; N = 6400;  oo = 104857600; }
    else if (x < 525) { k = 2; nt = x - 500; N = 1600;  oo = 131072000; }
    else if (x < 532) { k = 3; nt = x - 525; N = 400;   oo = 137625600; }
    else              { k = 4; nt = x - 532; N = 100;   oo = 139264000; }
}

// ---------------- Kernel 1: q partials, 4-way split over K ----------------
__global__ __launch_bounds__(256) void k_q(
    const float* __restrict__ modulator,  // [16][12544]
    const float* __restrict__ pm_w,       // [5][256][12544]
    float* __restrict__ qpart)            // [4][5][16][256]
{
    int o4 = blockIdx.x;                  // outputs o4 + {0,64,128,192}
    int k  = blockIdx.y;
    int s  = blockIdx.z;                  // K-split 0..3, 784 float4 each
    int t  = threadIdx.x;
    float acc[4][16];
#pragma unroll
    for (int j = 0; j < 4; ++j)
#pragma unroll
        for (int bi = 0; bi < 16; ++bi) acc[j][bi] = 0.f;
    const float4* mod4 = (const float4*)modulator;
    const float4* wp0 = (const float4*)(pm_w + ((size_t)k * 256 + o4      ) * 12544);
    const float4* wp1 = (const float4*)(pm_w + ((size_t)k * 256 + o4 +  64) * 12544);
    const float4* wp2 = (const float4*)(pm_w + ((size_t)k * 256 + o4 + 128) * 12544);
    const float4* wp3 = (const float4*)(pm_w + ((size_t)k * 256 + o4 + 192) * 12544);
    for (int it = 0; it < 4; ++it) {
        int jj = it * 256 + t;
        if (jj < 784) {
            int jx = s * 784 + jj;
            float4 wv0 = wp0[jx], wv1 = wp1[jx], wv2 = wp2[jx], wv3 = wp3[jx];
#pragma unroll
            for (int bi = 0; bi < 16; ++bi) {
                float4 m = mod4[bi * 3136 + jx];
                acc[0][bi] += wv0.x * m.x + wv0.y * m.y + wv0.z * m.z + wv0.w * m.w;
                acc[1][bi] += wv1.x * m.x + wv1.y * m.y + wv1.z * m.z + wv1.w * m.w;
                acc[2][bi] += wv2.x * m.x + wv2.y * m.y + wv2.z * m.z + wv2.w * m.w;
                acc[3][bi] += wv3.x * m.x + wv3.y * m.y + wv3.z * m.z + wv3.w * m.w;
            }
        }
    }
#pragma unroll
    for (int j = 0; j < 4; ++j)
#pragma unroll
        for (int bi = 0; bi < 16; ++bi)
#pragma unroll
            for (int off = 32; off > 0; off >>= 1)
                acc[j][bi] += __shfl_down(acc[j][bi], off);
    __shared__ float red[4][64];
    int w = t >> 6, lane = t & 63;
    if (lane == 0) {
#pragma unroll
        for (int j = 0; j < 4; ++j)
#pragma unroll
            for (int bi = 0; bi < 16; ++bi) red[w][j * 16 + bi] = acc[j][bi];
    }
    __syncthreads();
    if (t < 64) {
        float v = red[0][t] + red[1][t] + red[2][t] + red[3][t];
        int bi = t & 15;
        int o  = o4 + (t >> 4) * 64;
        qpart[(((size_t)s * 5 + k) * 16 + bi) * 256 + o] = v;
    }
}

// ---------------- Kernel 2: W2 = bf16(po_w * (sum qpart + pm_b)), 4c/thread
__global__ __launch_bounds__(256) void k_w2(
    const float* __restrict__ po_w,       // [5][256][256]
    const float* __restrict__ pm_b,       // [5][256]
    const float* __restrict__ qpart,      // [4][5][16][256]
    u16* __restrict__ w2)                 // [5][16][256][256] bf16
{
    int idx4 = blockIdx.x * 256 + threadIdx.x;   // 5*2^18 threads, 4 c each
    int c4 = idx4 & 63;
    int o  = (idx4 >> 6) & 255;
    int bi = (idx4 >> 14) & 15;
    int k  = idx4 >> 18;
    size_t qi = ((size_t)(k * 16 + bi)) * 256 + c4 * 4;
    f32x4 q0 = *(const f32x4*)(qpart + qi);
    f32x4 q1 = *(const f32x4*)(qpart + qi + 20480);
    f32x4 q2 = *(const f32x4*)(qpart + qi + 40960);
    f32x4 q3 = *(const f32x4*)(qpart + qi + 61440);
    f32x4 pb = *(const f32x4*)(pm_b + k * 256 + c4 * 4);
    f32x4 q  = q0 + q1 + q2 + q3 + pb;
    f32x4 w  = *(const f32x4*)(po_w + ((size_t)(k * 256 + o)) * 256 + c4 * 4);
    uint2 r;
    r.x = pack2(w[0] * q[0], w[1] * q[1]);
    r.y = pack2(w[2] * q[2], w[3] * q[3]);
    *(uint2*)(w2 + (size_t)idx4 * 4) = r;
}

// ---------------- Kernel 3: persistent fused transpose + GEMM --------------
// job j: tile = j>>2 (64n, level-0 first), b = j&3. Worker = blockIdx.x,
// jobs j = bid, bid+512, ... Each wave owns 32 o-rows; ni = 2 n-tiles of 32.

__device__ __forceinline__ void stage_load(const float* __restrict__ fsrc,
                                           int b, int N, int n0, int ng, int cq0,
                                           f32x4 stg[2][4]) {
    const bool inb = (n0 + ng * 4) < N;
    const float* s = fsrc + (size_t)b * 256 * N + n0 + ng * 4;
#pragma unroll
    for (int jj = 0; jj < 2; ++jj) {
        int cq = cq0 + 32 * jj;
#pragma unroll
        for (int r = 0; r < 4; ++r) {
            stg[jj][r] = (f32x4){0.f, 0.f, 0.f, 0.f};
            if (inb) stg[jj][r] = *(const f32x4*)(s + (size_t)(4 * cq + r) * N);
        }
    }
}

__device__ __forceinline__ void stage_write(u16* __restrict__ ldsbuf,
                                            int ng, int cq0, const f32x4 stg[2][4]) {
#pragma unroll
    for (int jj = 0; jj < 2; ++jj) {
        int cq = cq0 + 32 * jj;
#pragma unroll
        for (int e = 0; e < 4; ++e) {
            int n = ng * 4 + e;
            unsigned h = ((unsigned)n & 7u) ^ (((unsigned)n >> 2) & 7u);
            unsigned off = ((unsigned)n << 9) + ((unsigned)cq << 3);
            off ^= (h << 4);
            uint2 wv;
            wv.x = pack2(stg[jj][0][e], stg[jj][1][e]);
            wv.y = pack2(stg[jj][2][e], stg[jj][3][e]);
            *(uint2*)((char*)ldsbuf + off) = wv;
        }
    }
}

__global__ __launch_bounds__(512, 4) void k_gemm(
    const float* __restrict__ f0, const float* __restrict__ f1,
    const float* __restrict__ f2, const float* __restrict__ f3,
    const float* __restrict__ f4,
    const u16* __restrict__ w2,      // [k][bi][o][c] bf16 row-major
    const float* __restrict__ po_b,  // [5][256]
    float* __restrict__ out)         // [k][bi][o][n] fp32
{
    __shared__ __align__(16) u16 lds[2][64 * 256];   // 2 x 32 KB
    const int t = threadIdx.x;
    const int lane = t & 63, w = t >> 6;             // 8 waves, 32 o-rows each
    const int l31 = lane & 31, lg5 = lane >> 5;
    const int ng = t & 15, cq0 = t >> 4;             // staging layout

    // LDS read addressing (lane-only, hoisted): row = ni*32 + l31
    unsigned mrow[2], mx[2];
#pragma unroll
    for (int ni = 0; ni < 2; ++ni) {
        int row = ni * 32 + l31;
        unsigned h = ((unsigned)row & 7u) ^ (((unsigned)row >> 2) & 7u);
        mrow[ni] = (unsigned)row << 9;
        mx[ni] = ((unsigned)lg5 ^ h) << 4;
    }

    int job = blockIdx.x;
    int k, nt, N; size_t oo;
    decode_tile(job >> 2, k, nt, N, oo);
    int b = job & 3;

    f32x4 stg[2][4];
    {   // prologue: stage job0 into buffer 0
        const float* fsrc = (k == 0) ? f0 : (k == 1) ? f1 : (k == 2) ? f2 : (k == 3) ? f3 : f4;
        stage_load(fsrc, b, N, nt * 64, ng, cq0, stg);
        stage_write(lds[0], ng, cq0, stg);
    }
    asm volatile("s_waitcnt lgkmcnt(0)" ::: "memory");
    __builtin_amdgcn_s_barrier();

    int cur = 0;
    for (;;) {
        const int n0 = nt * 64;
        const char* Lc = (const char*)lds[cur];
        const float* pb = po_b + k * 256;
        f32x4 bias4[4];
#pragma unroll
        for (int m = 0; m < 4; ++m)
            bias4[m] = *(const f32x4*)(pb + w * 32 + 8 * m + 4 * lg5);

        const int jn = job + NWORK;
        const bool hn = jn < NJOBS;
        int k2 = 0, nt2 = 0, N2 = 0, b2 = 0; size_t oo2 = 0;
        if (hn) { decode_tile(jn >> 2, k2, nt2, N2, oo2); b2 = jn & 3; }

#pragma unroll
        for (int i = 0; i < 4; ++i) {
            const u16* wsrc = w2 + ((size_t)(k * 16 + b * 4 + i) << 16)
                            + (size_t)(w * 32 + l31) * 256 + lg5 * 8;
            float* obase = out + oo + (size_t)(b * 4 + i) * 256 * N;

            f32x16 acc[2];
#pragma unroll
            for (int ni = 0; ni < 2; ++ni)
#pragma unroll
                for (int q = 0; q < 16; ++q)
                    acc[ni][q] = bias4[q >> 2][q & 3];

#pragma unroll 4
            for (int kk = 0; kk < 16; ++kk) {       // K = 256 = 16 x 16
                bf16x8 a = *(const bf16x8*)(wsrc + kk * 16);
                unsigned kb = (unsigned)kk << 5;
                bf16x8 bb0 = *(const bf16x8*)(Lc + (mrow[0] + (kb ^ mx[0])));
                bf16x8 bb1 = *(const bf16x8*)(Lc + (mrow[1] + (kb ^ mx[1])));
                acc[0] = __builtin_amdgcn_mfma_f32_32x32x16_bf16(a, bb0, acc[0], 0, 0, 0);
                acc[1] = __builtin_amdgcn_mfma_f32_32x32x16_bf16(a, bb1, acc[1], 0, 0, 0);
            }

            // stores: D col = l31 (n), row = (q&3)+8*(q>>2)+4*lg5 (o); 2 full lines/instr
#pragma unroll
            for (int ni = 0; ni < 2; ++ni) {
                int ocol = n0 + ni * 32 + l31;
                if (ocol < N) {
                    float* op = obase + ocol;
#pragma unroll
                    for (int q = 0; q < 16; ++q) {
                        int orow = w * 32 + (q & 3) + 8 * (q >> 2) + 4 * lg5;
                        __builtin_nontemporal_store(acc[ni][q], op + (size_t)orow * N);
                    }
                }
            }

            if (i == 0 && hn) {
                // issue next tile's global loads AFTER inst0 (in-order vmcnt:
                // inst0's a-loads stay older -> their waits don't touch these)
                __builtin_amdgcn_sched_barrier(0);
                const float* fs2 = (k2 == 0) ? f0 : (k2 == 1) ? f1 : (k2 == 2) ? f2
                                 : (k2 == 3) ? f3 : f4;
                stage_load(fs2, b2, N2, nt2 * 64, ng, cq0, stg);
                __builtin_amdgcn_sched_barrier(0);
            }
            if (i == 2 && hn) {
                // write next tile; compiler waits vmcnt only down to the
                // stage loads (stores issued after them may stay in flight)
                stage_write((u16*)lds[cur ^ 1], ng, cq0, stg);
            }
        }

        // raw barrier: only LDS drained; global stores float across jobs
        asm volatile("s_waitcnt lgkmcnt(0)" ::: "memory");
        __builtin_amdgcn_s_barrier();

        if (!hn) break;
        job = jn; k = k2; nt = nt2; N = N2; oo = oo2; b = b2; cur ^= 1;
    }
}

// ---------------------------------------------------------------------------
extern "C" void kernel_launch(void* const* d_in, const int* in_sizes, int n_in,
                              void* d_out, int out_size, void* d_ws, size_t ws_size,
                              hipStream_t stream) {
    const float* f0 = (const float*)d_in[0];
    const float* f1 = (const float*)d_in[1];
    const float* f2 = (const float*)d_in[2];
    const float* f3 = (const float*)d_in[3];
    const float* f4 = (const float*)d_in[4];
    const float* modulator = (const float*)d_in[5];
    const float* pm_w = (const float*)d_in[6];
    const float* pm_b = (const float*)d_in[7];
    const float* po_w = (const float*)d_in[8];
    const float* po_b = (const float*)d_in[9];
    float* out = (float*)d_out;

    // workspace: w2 bf16 (5,242,880 u16) | qpart (81,920 f32)  ~= 10.8 MB
    u16* w2 = (u16*)d_ws;
    float* qpart = (float*)(w2 + (size_t)5 * 16 * 256 * 256);

    k_q<<<dim3(64, 5, 4), 256, 0, stream>>>(modulator, pm_w, qpart);
    k_w2<<<5120, 256, 0, stream>>>(po_w, pm_b, qpart, w2);
    k_gemm<<<NWORK, 512, 0, stream>>>(f0, f1, f2, f3, f4, w2, po_b, out);
}

// Round 5
// 229.044 us; speedup vs baseline: 1.1142x; 1.1142x over previous
//
#include <hip/hip_runtime.h>
#include <hip/hip_bf16.h>

// ---------------------------------------------------------------------------
// RPN_Modulator fused pipeline (3 kernels):
//   k_q   : qpart[s,k,bi,c] = partial_c' modulator[bi,c'] * pm_w[k,c,c']   (4-way K-split)
//   k_w2  : w2[k,bi,o,c] = bf16(po_w[k,o,c] * (sum_s qpart + pm_b[k,c]))   (row-major)
//   k_gemm: out[k,bi,o,n] = sum_c w2[o,c]*bf16(feats[k][b,c,n]) + po_b[k,o]
//
// Round-4: REVERT the persistent rewrite (255us: 64-tile halved MFMA/byte and
// sched_barrier-pinned reg staging serialized against NT-store drain via
// in-order vmcnt). Back to the verified round-3 k_gemm (193us) with ONE
// change: grid 1072 -> 1024 blocks + 2-iteration grid-stride loop. 1072
// uniform jobs over 512 resident slots was 3 scheduling generations
// (512+512+48, wall ~3d); now exactly 2 generations -- the 48 double-duty
// blocks are bids 0..47 (dispatched first), their second job = the lighter
// masked tail tiles (jobs 1024..1071). Flatten b=j/268, tile=j%268 keeps
// consecutive bids on same-b adjacent tiles (w2 L2 reuse). Extra guarded
// __syncthreads only for the 48 looping blocks.
// ---------------------------------------------------------------------------

typedef __bf16 bf16x8 __attribute__((ext_vector_type(8)));
typedef float  f32x4  __attribute__((ext_vector_type(4)));
typedef float  f32x16 __attribute__((ext_vector_type(16)));
typedef unsigned short u16;

#define NJOBS 1072   // 268 tiles * 4 b
#define NWORK 1024

__device__ __forceinline__ unsigned pack2(float lo, float hi) {
    __hip_bfloat162 h = __float22bfloat162_rn(make_float2(lo, hi));
    union { __hip_bfloat162 h; unsigned u; } cv; cv.h = h; return cv.u;
}

// tiles-of-128 per level: {200,50,13,4,1}, total 268
__device__ __forceinline__ void decode_tile(int x, int& k, int& nt, int& N, size_t& oo) {
    if (x < 200)      { k = 0; nt = x;       N = 25600; oo = 0; }
    else if (x < 250) { k = 1; nt = x - 200; N = 6400;  oo = 104857600; }
    else if (x < 263) { k = 2; nt = x - 250; N = 1600;  oo = 131072000; }
    else if (x < 267) { k = 3; nt = x - 263; N = 400;   oo = 137625600; }
    else              { k = 4; nt = x - 267; N = 100;   oo = 139264000; }
}

// ---------------- Kernel 1: q partials, 4-way split over K ----------------
__global__ __launch_bounds__(256) void k_q(
    const float* __restrict__ modulator,  // [16][12544]
    const float* __restrict__ pm_w,       // [5][256][12544]
    float* __restrict__ qpart)            // [4][5][16][256]
{
    int o4 = blockIdx.x;                  // outputs o4 + {0,64,128,192}
    int k  = blockIdx.y;
    int s  = blockIdx.z;                  // K-split 0..3, 784 float4 each
    int t  = threadIdx.x;
    float acc[4][16];
#pragma unroll
    for (int j = 0; j < 4; ++j)
#pragma unroll
        for (int bi = 0; bi < 16; ++bi) acc[j][bi] = 0.f;
    const float4* mod4 = (const float4*)modulator;
    const float4* wp0 = (const float4*)(pm_w + ((size_t)k * 256 + o4      ) * 12544);
    const float4* wp1 = (const float4*)(pm_w + ((size_t)k * 256 + o4 +  64) * 12544);
    const float4* wp2 = (const float4*)(pm_w + ((size_t)k * 256 + o4 + 128) * 12544);
    const float4* wp3 = (const float4*)(pm_w + ((size_t)k * 256 + o4 + 192) * 12544);
    for (int it = 0; it < 4; ++it) {
        int jj = it * 256 + t;
        if (jj < 784) {
            int jx = s * 784 + jj;
            float4 wv0 = wp0[jx], wv1 = wp1[jx], wv2 = wp2[jx], wv3 = wp3[jx];
#pragma unroll
            for (int bi = 0; bi < 16; ++bi) {
                float4 m = mod4[bi * 3136 + jx];
                acc[0][bi] += wv0.x * m.x + wv0.y * m.y + wv0.z * m.z + wv0.w * m.w;
                acc[1][bi] += wv1.x * m.x + wv1.y * m.y + wv1.z * m.z + wv1.w * m.w;
                acc[2][bi] += wv2.x * m.x + wv2.y * m.y + wv2.z * m.z + wv2.w * m.w;
                acc[3][bi] += wv3.x * m.x + wv3.y * m.y + wv3.z * m.z + wv3.w * m.w;
            }
        }
    }
#pragma unroll
    for (int j = 0; j < 4; ++j)
#pragma unroll
        for (int bi = 0; bi < 16; ++bi)
#pragma unroll
            for (int off = 32; off > 0; off >>= 1)
                acc[j][bi] += __shfl_down(acc[j][bi], off);
    __shared__ float red[4][64];
    int w = t >> 6, lane = t & 63;
    if (lane == 0) {
#pragma unroll
        for (int j = 0; j < 4; ++j)
#pragma unroll
            for (int bi = 0; bi < 16; ++bi) red[w][j * 16 + bi] = acc[j][bi];
    }
    __syncthreads();
    if (t < 64) {
        float v = red[0][t] + red[1][t] + red[2][t] + red[3][t];
        int bi = t & 15;
        int o  = o4 + (t >> 4) * 64;
        qpart[(((size_t)s * 5 + k) * 16 + bi) * 256 + o] = v;
    }
}

// ---------------- Kernel 2: W2 = bf16(po_w * (sum qpart + pm_b)), 4c/thread
__global__ __launch_bounds__(256) void k_w2(
    const float* __restrict__ po_w,       // [5][256][256]
    const float* __restrict__ pm_b,       // [5][256]
    const float* __restrict__ qpart,      // [4][5][16][256]
    u16* __restrict__ w2)                 // [5][16][256][256] bf16
{
    int idx4 = blockIdx.x * 256 + threadIdx.x;   // 5*2^18 threads, 4 c each
    int c4 = idx4 & 63;
    int o  = (idx4 >> 6) & 255;
    int bi = (idx4 >> 14) & 15;
    int k  = idx4 >> 18;
    size_t qi = ((size_t)(k * 16 + bi)) * 256 + c4 * 4;
    f32x4 q0 = *(const f32x4*)(qpart + qi);
    f32x4 q1 = *(const f32x4*)(qpart + qi + 20480);
    f32x4 q2 = *(const f32x4*)(qpart + qi + 40960);
    f32x4 q3 = *(const f32x4*)(qpart + qi + 61440);
    f32x4 pb = *(const f32x4*)(pm_b + k * 256 + c4 * 4);
    f32x4 q  = q0 + q1 + q2 + q3 + pb;
    f32x4 w  = *(const f32x4*)(po_w + ((size_t)(k * 256 + o)) * 256 + c4 * 4);
    uint2 r;
    r.x = pack2(w[0] * q[0], w[1] * q[1]);
    r.y = pack2(w[2] * q[2], w[3] * q[3]);
    *(uint2*)(w2 + (size_t)idx4 * 4) = r;
}

// ---------------- Kernel 3: fused transpose + GEMM over all levels ---------
// 1024 blocks x 2-iteration stride loop over 1072 jobs (tile128, b).
// block: 512 threads = 8 waves; 128 out-cols x full M=256 x 4 instances;
// each wave owns 32 o-rows via ONE 32-row m-tile, 4 n-tiles of 32 (32x32x16
// MFMA, acc 4 x f32x16). LDS: feats [128n][256c] bf16, h-swizzled. A direct
// from L2-resident w2. Every store instr = two full 128B lines.
__global__ __launch_bounds__(512, 4) void k_gemm(
    const float* __restrict__ f0, const float* __restrict__ f1,
    const float* __restrict__ f2, const float* __restrict__ f3,
    const float* __restrict__ f4,
    const u16* __restrict__ w2,      // [k][bi][o][c] bf16 row-major
    const float* __restrict__ po_b,  // [5][256]
    float* __restrict__ out)         // [k][bi][o][n] fp32
{
    __shared__ __align__(16) u16 ldsB[128 * 256];   // 64 KB
    const int t = threadIdx.x;
    const int lane = t & 63, w = t >> 6;        // 8 waves, 32 o-rows each
    const int l31 = lane & 31, lg5 = lane >> 5;

    // B (feats) LDS addressing (lane-only, hoisted): row = ni*32 + l31
    unsigned mrow[4], mx[4];
#pragma unroll
    for (int ni = 0; ni < 4; ++ni) {
        int row = ni * 32 + l31;
        unsigned h = ((unsigned)row & 7u) ^ (((unsigned)row >> 2) & 7u);
        mrow[ni] = (unsigned)row << 9;
        mx[ni] = ((unsigned)lg5 ^ h) << 4;
    }

    for (int j = blockIdx.x; j < NJOBS; j += NWORK) {
        const int b = j / 268;
        const int tile = j - b * 268;
        int k, nt, N; size_t oo;
        decode_tile(tile, k, nt, N, oo);
        const float* fsrc = (k == 0) ? f0 : (k == 1) ? f1 : (k == 2) ? f2 : (k == 3) ? f3 : f4;
        const int n0 = nt * 128;

        if (j != (int)blockIdx.x) __syncthreads();   // protect LDS overwrite (2nd iter only)

        // ---- stage: fp32 [c][n] -> bf16 LDS [n][c], h-swizzled b64 writes ----
        {
            const int ng = t & 31, grp = t >> 5;    // ng: float4 along n; grp 0..15
            const bool inb = (n0 + ng * 4) < N;     // N%4==0 -> whole float4 in/out
            const float* s = fsrc + (size_t)b * 256 * N + n0 + ng * 4;
#pragma unroll
            for (int jj = 0; jj < 4; ++jj) {
                int q = jj * 16 + grp;              // c-quad: c = 4q..4q+3
                f32x4 v0 = {0.f,0.f,0.f,0.f}, v1 = {0.f,0.f,0.f,0.f};
                f32x4 v2 = {0.f,0.f,0.f,0.f}, v3 = {0.f,0.f,0.f,0.f};
                if (inb) {
                    v0 = *(const f32x4*)(s + (size_t)(4 * q + 0) * N);
                    v1 = *(const f32x4*)(s + (size_t)(4 * q + 1) * N);
                    v2 = *(const f32x4*)(s + (size_t)(4 * q + 2) * N);
                    v3 = *(const f32x4*)(s + (size_t)(4 * q + 3) * N);
                }
#pragma unroll
                for (int e = 0; e < 4; ++e) {
                    int n = ng * 4 + e;
                    unsigned h = ((unsigned)n & 7u) ^ (((unsigned)n >> 2) & 7u);
                    unsigned off = ((unsigned)n << 9) + ((unsigned)q << 3);
                    off ^= (h << 4);
                    uint2 wv; wv.x = pack2(v0[e], v1[e]); wv.y = pack2(v2[e], v3[e]);
                    *(uint2*)((char*)ldsB + off) = wv;
                }
            }
        }
        __syncthreads();

        const float* pb = po_b + k * 256;
        float* obase0 = out + oo;

        // bias: rows for acc reg q are w*32 + (q&3) + 8*(q>>2) + 4*lg5
        f32x4 bias4[4];
#pragma unroll
        for (int m = 0; m < 4; ++m)
            bias4[m] = *(const f32x4*)(pb + w * 32 + 8 * m + 4 * lg5);

#pragma unroll 1
        for (int i = 0; i < 4; ++i) {
            // A (w2): row = w*32 + l31, k-bytes = kk*32 + lg5*16
            const u16* wsrc = w2 + ((size_t)(k * 16 + b * 4 + i) << 16)
                            + (size_t)(w * 32 + l31) * 256 + lg5 * 8;
            float* obase = obase0 + (size_t)(b * 4 + i) * 256 * N;

            f32x16 acc[4];
#pragma unroll
            for (int ni = 0; ni < 4; ++ni)
#pragma unroll
                for (int q = 0; q < 16; ++q)
                    acc[ni][q] = bias4[q >> 2][q & 3];

#pragma unroll 2
            for (int kk = 0; kk < 16; ++kk) {       // K = 256 = 16 x 16
                bf16x8 a = *(const bf16x8*)(wsrc + kk * 16);
                bf16x8 bb[4];
                unsigned kb = (unsigned)kk << 5;
#pragma unroll
                for (int ni = 0; ni < 4; ++ni)
                    bb[ni] = *(const bf16x8*)((const char*)ldsB + (mrow[ni] + (kb ^ mx[ni])));
#pragma unroll
                for (int ni = 0; ni < 4; ++ni)
                    acc[ni] = __builtin_amdgcn_mfma_f32_32x32x16_bf16(a, bb[ni], acc[ni], 0, 0, 0);
            }

            // epilogue: D col = l31 (n), row = (q&3)+8*(q>>2)+4*lg5 (o).
            // Each store instr: 2 row-groups x 32 consecutive n = 2 full lines.
#pragma unroll
            for (int ni = 0; ni < 4; ++ni) {
                int ocol = n0 + ni * 32 + l31;
                if (ocol < N) {
                    float* op = obase + ocol;
#pragma unroll
                    for (int q = 0; q < 16; ++q) {
                        int orow = w * 32 + (q & 3) + 8 * (q >> 2) + 4 * lg5;
                        __builtin_nontemporal_store(acc[ni][q], op + (size_t)orow * N);
                    }
                }
            }
        }
    }
}

// ---------------------------------------------------------------------------
extern "C" void kernel_launch(void* const* d_in, const int* in_sizes, int n_in,
                              void* d_out, int out_size, void* d_ws, size_t ws_size,
                              hipStream_t stream) {
    const float* f0 = (const float*)d_in[0];
    const float* f1 = (const float*)d_in[1];
    const float* f2 = (const float*)d_in[2];
    const float* f3 = (const float*)d_in[3];
    const float* f4 = (const float*)d_in[4];
    const float* modulator = (const float*)d_in[5];
    const float* pm_w = (const float*)d_in[6];
    const float* pm_b = (const float*)d_in[7];
    const float* po_w = (const float*)d_in[8];
    const float* po_b = (const float*)d_in[9];
    float* out = (float*)d_out;

    // workspace: w2 bf16 (5,242,880 u16) | qpart (81,920 f32)  ~= 10.8 MB
    u16* w2 = (u16*)d_ws;
    float* qpart = (float*)(w2 + (size_t)5 * 16 * 256 * 256);

    k_q<<<dim3(64, 5, 4), 256, 0, stream>>>(modulator, pm_w, qpart);
    k_w2<<<5120, 256, 0, stream>>>(po_w, pm_b, qpart, w2);
    k_gemm<<<NWORK, 512, 0, stream>>>(f0, f1, f2, f3, f4, w2, po_b, out);
}